// Round 1
// baseline (17347.095 us; speedup 1.0000x reference)
//
#include <hip/hip_runtime.h>
#include <math.h>
#include <stdint.h>

// Problem dims
#define NB 16384    // batch
#define NH 768      // hidden
#define ND 784      // input features
#define NC 10       // classes
#define NW 12       // u64 words per 768-bit row

// gemm1 tiling
#define XP 788      // xs row pitch (f32): 788 % 32 == 20 -> 8 rows spread over 8 bank-groups
#define WP 212      // wcs col pitch (f32): 212 % 32 == 20 -> 8 cols spread; fits 208 elems
#define CK 192      // k-chunk (chunks 0..2); chunk 3 covers 208 (192 + 16 tail)

// ---------------------------------------------------------------------------
// prep: BN params in FAITHFUL f32 (replicating np op-by-op):
// sc = g * (1 / sqrt(v + 1e-5)), each op f32-rounded. [0]=sc,[1]=m,[2]=be,[3]=bias
// ---------------------------------------------------------------------------
__global__ void k_bnprep_f32(const float* __restrict__ g, const float* __restrict__ be,
                             const float* __restrict__ m, const float* __restrict__ v,
                             const float* __restrict__ bias, float* __restrict__ out) {
    int i = blockIdx.x * 256 + threadIdx.x;
    if (i >= NH) return;
    float t1 = __fadd_rn(v[i], 1e-5f);
    float t2 = __fsqrt_rn(t1);
    float t3 = __fdiv_rn(1.0f, t2);
    out[i]          = __fmul_rn(g[i], t3);
    out[NH + i]     = m[i];
    out[2 * NH + i] = be[i];
    out[3 * NH + i] = bias[i];
}

// ---------------------------------------------------------------------------
// prep: W1 signs as f32 +/-1 (no per-use unpack in the GEMM hot loop).
// Written into the (otherwise still-unused) h3 region of the workspace.
// ---------------------------------------------------------------------------
__global__ void k_pack_w1f32(const float* __restrict__ W1, float* __restrict__ wf) {
    int i = blockIdx.x * 256 + threadIdx.x;
    if (i < NH * ND) wf[i] = (W1[i] >= 0.0f) ? 1.0f : -1.0f;
}

// ---------------------------------------------------------------------------
// prep: W2/W3 sign bits, transposed words: wT[j*768 + col] bit l = (W[col][j*64+l] >= 0)
// ---------------------------------------------------------------------------
__global__ void k_pack_wT(const float* __restrict__ W, unsigned long long* __restrict__ wT) {
    int idx = blockIdx.x * 256 + threadIdx.x;
    if (idx >= NH * NW) return;
    int col = idx / NW, j = idx % NW;
    unsigned long long w = 0ull;
    for (int l = 0; l < 64; ++l) {
        float v = W[(size_t)col * NH + j * 64 + l];
        w |= (unsigned long long)(v >= 0.0f ? 1 : 0) << l;
    }
    wT[(size_t)j * NH + col] = w;
}

// ---------------------------------------------------------------------------
// GEMM1 replicating numpy einsum sum_of_products_contig_two (AVX512 npyv),
// bit-identical to the previous (passing) kernel:
//   - 64 chains per (row,col): chain e accumulates k = t*64+e, t ascending,
//     tail k=768..783 into chains e=0..15
//   - combine v_jh[i] = (a_g0+a_g1)+(a_g2+a_g3); h8[i]=v_0[i]+v_1[i];
//     tree 8/4/2/1. All __fmaf_rn/__fadd_rn, identical op order.
// R10 vs R9 (math identical, structure new):
//   - thread = ONE (row,col) pair, ALL 64 chains in registers -> reduce is
//     fully local (63 adds, zero shuffles)
//   - wave = 8 rows x 8 cols -> every ds_read_b128 is 8 distinct 16B lines
//     x 8-way broadcast; pitches 788/212 make them bank-conflict-free
//   - weights staged as f32 +/-1 (unpack eliminated entirely); w amortized
//     over 8 rows per read instead of 1
//   - per 64-k supertile: 64 FMA + 32 ds_read (FMA ~80% of issue vs ~45%)
// Block: 512 thr = 8 waves (wave w owns cols w*8..w*8+7, rows 0..7);
// grid (NB/8, NH/64); LDS 79,552 B -> 2 blocks/CU.
// ---------------------------------------------------------------------------
#define FMA8(E, wA, wB, xA, xB)                                    \
    a[(E) + 0] = __fmaf_rn((wA).x, (xA).x, a[(E) + 0]);            \
    a[(E) + 1] = __fmaf_rn((wA).y, (xA).y, a[(E) + 1]);            \
    a[(E) + 2] = __fmaf_rn((wA).z, (xA).z, a[(E) + 2]);            \
    a[(E) + 3] = __fmaf_rn((wA).w, (xA).w, a[(E) + 3]);            \
    a[(E) + 4] = __fmaf_rn((wB).x, (xB).x, a[(E) + 4]);            \
    a[(E) + 5] = __fmaf_rn((wB).y, (xB).y, a[(E) + 5]);            \
    a[(E) + 6] = __fmaf_rn((wB).z, (xB).z, a[(E) + 6]);            \
    a[(E) + 7] = __fmaf_rn((wB).w, (xB).w, a[(E) + 7])

__global__ __launch_bounds__(512, 4)
void k_gemm1_f(const float* __restrict__ x, const float* __restrict__ wf,
               const float* __restrict__ bnp, unsigned int* __restrict__ s1p32) {
    __shared__ alignas(16) float xs[8][XP];    // 25,216 B
    __shared__ alignas(16) float wcs[64][WP];  // 54,272 B
    __shared__ unsigned int sbits[16];         // [8 rows][2 u32 words]

    const int tid = threadIdx.x;
    const int wave = tid >> 6, lane = tid & 63;
    const int r = lane >> 3, c = lane & 7;     // this thread's (row, col-sub)
    const int r0 = blockIdx.x * 8;
    const int cb = blockIdx.y * 64;

    // stage x: wave w stages row w (consecutive b128, conflict-free, wave-coherent)
    {
        const float4* src = (const float4*)(x + (size_t)(r0 + wave) * ND);
        for (int k4 = lane; k4 < ND / 4; k4 += 64)
            *(float4*)&xs[wave][k4 * 4] = src[k4];
    }

    float a[64];
#pragma unroll
    for (int e = 0; e < 64; ++e) a[e] = 0.0f;

    const float* xb = &xs[r][0];
    const float* wb = &wcs[wave * 8 + c][0];

#pragma unroll 1
    for (int cc = 0; cc < 4; ++cc) {
        const int k0 = cc * CK;                       // 0,192,384,576
        const int nk4 = (cc < 3) ? (CK / 4) : ((CK + 16) / 4);  // 48 / 52
        __syncthreads();  // all waves done reading previous wcs chunk (cc=0: orders xs too)
        // stage w chunk: wave stages its own 8 cols, f32 +/-1, consecutive b128 per col
#pragma unroll
        for (int q = 0; q < 8; ++q) {
            const int col = wave * 8 + q;
            if (lane < nk4) {
                float4 v = *(const float4*)(wf + (size_t)(cb + col) * ND + (k0 + lane * 4));
                *(float4*)&wcs[col][lane * 4] = v;
            }
        }
        __syncthreads();

        const float* xp = xb + k0;
#pragma unroll
        for (int tl = 0; tl < 3; ++tl) {              // 3 supertiles of 64 k per chunk
#pragma unroll
            for (int q8 = 0; q8 < 8; ++q8) {          // chain e = q8*8 + u (indep of tl)
                const int ko = tl * 64 + q8 * 8;
                float4 xA = *(const float4*)(xp + ko);
                float4 xB = *(const float4*)(xp + ko + 4);
                float4 wA = *(const float4*)(wb + ko);
                float4 wB = *(const float4*)(wb + ko + 4);
                FMA8(q8 * 8, wA, wB, xA, xB);
            }
        }
        if (cc == 3) {
            // tail k = 768..783 -> chains e = 0..15 (ascending, after t=11)
#pragma unroll
            for (int q8 = 0; q8 < 2; ++q8) {
                const int ko = 192 + q8 * 8;
                float4 xA = *(const float4*)(xp + ko);
                float4 xB = *(const float4*)(xp + ko + 4);
                float4 wA = *(const float4*)(wb + ko);
                float4 wB = *(const float4*)(wb + ko + 4);
                FMA8(q8 * 8, wA, wB, xA, xB);
            }
        }
    }

    // -------- combine: exact tree, fully thread-local --------
    if (tid < 16) sbits[tid] = 0;
    __syncthreads();

    float h8[8];
#pragma unroll
    for (int i = 0; i < 8; ++i) {
        // v_jh = (a_g0 + a_g1) + (a_g2 + a_g3), chain e = g*16 + jh*8 + i
        float v0 = __fadd_rn(__fadd_rn(a[i],     a[16 + i]), __fadd_rn(a[32 + i], a[48 + i]));
        float v1 = __fadd_rn(__fadd_rn(a[8 + i], a[24 + i]), __fadd_rn(a[40 + i], a[56 + i]));
        h8[i] = __fadd_rn(v0, v1);
    }
    float h4[4], h2[2];
#pragma unroll
    for (int i = 0; i < 4; ++i) h4[i] = __fadd_rn(h8[i], h8[i + 4]);
#pragma unroll
    for (int i = 0; i < 2; ++i) h2[i] = __fadd_rn(h4[i], h4[i + 2]);
    float acc = __fadd_rn(h2[0], h2[1]);

    // epilogue: + b1, BN1 f32 op-by-op, sign -> packed bits
    const int col = cb + wave * 8 + c;
    const float sc = bnp[col], mm = bnp[NH + col], be = bnp[2 * NH + col],
                bias = bnp[3 * NH + col];
    float h  = __fadd_rn(acc, bias);
    float t1 = __fsub_rn(h, mm);
    float u  = __fmul_rn(t1, sc);
    float hb = __fadd_rn(u, be);
    unsigned long long bal = __ballot(hb >= 0.0f);   // bit (8*row + colsub) per lane
    if (lane < 8) {
        unsigned int b = (unsigned int)((bal >> (8 * lane)) & 0xFFull);  // row=lane's byte
        atomicOr(&sbits[lane * 2 + (wave >> 2)], b << ((wave & 3) * 8));
    }
    __syncthreads();
    if (tid < 16)
        s1p32[(size_t)(r0 + (tid >> 1)) * (2 * NW) + blockIdx.y * 2 + (tid & 1)] =
            sbits[tid];
}

// ---------------------------------------------------------------------------
// Binary layers 2/3: dot = 768 - 2*popcount(a XOR w) — exact integer, matches
// any-order f32 evaluation of +/-1 GEMM bit-for-bit (all partials exact).
// Epilogue faithful f32: h = fl(dot + b), BN op-by-op.
// MODE 0: sign -> packed bits. MODE 1: hardtanh -> f32 out.
// ---------------------------------------------------------------------------
template <int MODE>
__global__ __launch_bounds__(256, 2)
void k_popbin(const unsigned long long* __restrict__ Ap,
              const unsigned long long* __restrict__ wT,
              const float* __restrict__ bnp,
              unsigned long long* __restrict__ Sp, float* __restrict__ h_out) {
    __shared__ unsigned long long as[64][NW];
    const int tid = threadIdx.x;
    const int b0 = blockIdx.x * 64;

    {
        unsigned long long* asf = &as[0][0];
        const unsigned long long* src = Ap + (size_t)b0 * NW;
        for (int i = tid; i < 64 * NW; i += 256) asf[i] = src[i];
    }
    __syncthreads();

    const int wave = tid >> 6, lane = tid & 63;

    for (int chunk = 0; chunk < NW; ++chunk) {
        const int col = chunk * 64 + lane;
        unsigned long long w[NW];
#pragma unroll
        for (int j = 0; j < NW; ++j) w[j] = wT[(size_t)j * NH + col];
        const float sc = bnp[col], mm = bnp[NH + col], be = bnp[2 * NH + col],
                    bias = bnp[3 * NH + col];
        for (int r = 0; r < 16; ++r) {
            const int row = wave * 16 + r;
            int d = 0;
#pragma unroll
            for (int j = 0; j < NW; ++j)
                d += __builtin_popcountll(as[row][j] ^ w[j]);
            int dot = NH - 2 * d;
            float h  = __fadd_rn((float)dot, bias);
            float t  = __fsub_rn(h, mm);
            float u  = __fmul_rn(t, sc);
            float hb = __fadd_rn(u, be);
            if (MODE == 0) {
                unsigned long long word = __ballot(hb >= 0.0f);
                if (lane == 0) Sp[(size_t)(b0 + row) * NW + chunk] = word;
            } else {
                float hc = fminf(fmaxf(hb, -1.0f), 1.0f);
                h_out[(size_t)(b0 + row) * NH + col] = hc;
            }
        }
    }
}

// ---------------------------------------------------------------------------
// fc4 + log_softmax: one wave per row, double accumulation + shuffle reduce
// ---------------------------------------------------------------------------
__global__ __launch_bounds__(256, 4)
void k_fc4(const float* __restrict__ h3, const float* __restrict__ W4,
           const float* __restrict__ b4, float* __restrict__ out) {
    __shared__ float w4s[NC * NH];
    const int tid = threadIdx.x;
    for (int i = tid; i < NC * NH; i += 256) w4s[i] = W4[i];
    __syncthreads();

    const int wave = tid >> 6, lane = tid & 63;
    const int row = blockIdx.x * 4 + wave;
    const float* hrow = h3 + (size_t)row * NH;

    double p[NC];
#pragma unroll
    for (int c = 0; c < NC; ++c) p[c] = 0.0;

    for (int it = 0; it < NH / 64; ++it) {
        int j = it * 64 + lane;
        double hv = (double)hrow[j];
#pragma unroll
        for (int c = 0; c < NC; ++c) p[c] += hv * (double)w4s[c * NH + j];
    }
#pragma unroll
    for (int c = 0; c < NC; ++c) {
#pragma unroll
        for (int off = 32; off > 0; off >>= 1) p[c] += __shfl_xor(p[c], off, 64);
    }
    double lg[NC];
    double mx = -1e300;
#pragma unroll
    for (int c = 0; c < NC; ++c) {
        lg[c] = p[c] + (double)b4[c];
        mx = fmax(mx, lg[c]);
    }
    double s = 0.0;
#pragma unroll
    for (int c = 0; c < NC; ++c) s += exp(lg[c] - mx);
    double lse = mx + log(s);
    if (lane < NC) {
        double v = 0.0;
#pragma unroll
        for (int c = 0; c < NC; ++c)
            if (lane == c) v = lg[c];
        out[(size_t)row * NC + lane] = (float)(v - lse);
    }
}

// ---------------------------------------------------------------------------
// launch
// ---------------------------------------------------------------------------
extern "C" void kernel_launch(void* const* d_in, const int* in_sizes, int n_in,
                              void* d_out, int out_size, void* d_ws, size_t ws_size,
                              hipStream_t stream) {
    const float* x  = (const float*)d_in[0];
    const float* W1 = (const float*)d_in[1];
    const float* b1 = (const float*)d_in[2];
    const float* W2 = (const float*)d_in[3];
    const float* b2 = (const float*)d_in[4];
    const float* W3 = (const float*)d_in[5];
    const float* b3 = (const float*)d_in[6];
    const float* W4 = (const float*)d_in[7];
    const float* b4 = (const float*)d_in[8];
    const float* g1 = (const float*)d_in[9],  *be1 = (const float*)d_in[10];
    const float* m1 = (const float*)d_in[11], *v1  = (const float*)d_in[12];
    const float* g2 = (const float*)d_in[13], *be2 = (const float*)d_in[14];
    const float* m2 = (const float*)d_in[15], *v2  = (const float*)d_in[16];
    const float* g3 = (const float*)d_in[17], *be3 = (const float*)d_in[18];
    const float* m3 = (const float*)d_in[19], *v3  = (const float*)d_in[20];
    float* out = (float*)d_out;

    char* ws = (char*)d_ws;
    size_t off = 0;
    unsigned long long* w2pT = (unsigned long long*)(ws + off); off += (size_t)NW * NH * 8;
    unsigned long long* w3pT = (unsigned long long*)(ws + off); off += (size_t)NW * NH * 8;
    unsigned long long* s1p  = (unsigned long long*)(ws + off); off += (size_t)NB * NW * 8;
    unsigned long long* s2p  = (unsigned long long*)(ws + off); off += (size_t)NB * NW * 8;
    float*  h3   = (float*)(ws + off);              off += (size_t)NB * NH * 4;
    float* bnp1 = (float*)(ws + off);               off += (size_t)4 * NH * 4;
    float* bnp2 = (float*)(ws + off);               off += (size_t)4 * NH * 4;
    float* bnp3 = (float*)(ws + off);               off += (size_t)4 * NH * 4;
    (void)ws_size; (void)in_sizes; (void)n_in; (void)out_size;

    // wf32 (W1 signs as f32 +/-1, 2.4 MB) aliases h3: h3 is only written by
    // k_popbin<1>, which runs strictly after k_gemm1_f finishes reading wf32
    // (same stream). Saves workspace.
    float* wf32 = h3;

    // prep
    k_pack_w1f32<<<dim3((NH * ND + 255) / 256), 256, 0, stream>>>(W1, wf32);
    k_pack_wT<<<dim3((NH * NW + 255) / 256), 256, 0, stream>>>(W2, w2pT);
    k_pack_wT<<<dim3((NH * NW + 255) / 256), 256, 0, stream>>>(W3, w3pT);
    k_bnprep_f32<<<dim3(3), 256, 0, stream>>>(g1, be1, m1, v1, b1, bnp1);
    k_bnprep_f32<<<dim3(3), 256, 0, stream>>>(g2, be2, m2, v2, b2, bnp2);
    k_bnprep_f32<<<dim3(3), 256, 0, stream>>>(g3, be3, m3, v3, b3, bnp3);

    // layers
    k_gemm1_f<<<dim3(NB / 8, NH / 64), 512, 0, stream>>>(x, wf32, bnp1,
                                                         (unsigned int*)s1p);
    k_popbin<0><<<dim3(NB / 64), 256, 0, stream>>>(s1p, w2pT, bnp2, s2p, nullptr);
    k_popbin<1><<<dim3(NB / 64), 256, 0, stream>>>(s2p, w3pT, bnp3, nullptr, h3);
    k_fc4<<<dim3(NB / 4), 256, 0, stream>>>(h3, W4, b4, out);
}

// Round 2
// 12498.763 us; speedup vs baseline: 1.3879x; 1.3879x over previous
//
#include <hip/hip_runtime.h>
#include <math.h>
#include <stdint.h>

// Problem dims
#define NB 16384    // batch
#define NH 768      // hidden
#define ND 784      // input features
#define NC 10       // classes
#define NW 12       // u64 words per 768-bit row

// gemm1 tiling
#define XP 788      // xs row pitch (f32): 3152 B = 197 quads, 197%8=5 odd -> conflict-free b128
#define WPB 408     // wl col pitch (bf16): 816 B = 51 quads, 51%8=3 odd -> conflict-free b128

// ---------------------------------------------------------------------------
// prep: BN params in FAITHFUL f32 (replicating np op-by-op):
// sc = g * (1 / sqrt(v + 1e-5)), each op f32-rounded. [0]=sc,[1]=m,[2]=be,[3]=bias
// ---------------------------------------------------------------------------
__global__ void k_bnprep_f32(const float* __restrict__ g, const float* __restrict__ be,
                             const float* __restrict__ m, const float* __restrict__ v,
                             const float* __restrict__ bias, float* __restrict__ out) {
    int i = blockIdx.x * 256 + threadIdx.x;
    if (i >= NH) return;
    float t1 = __fadd_rn(v[i], 1e-5f);
    float t2 = __fsqrt_rn(t1);
    float t3 = __fdiv_rn(1.0f, t2);
    out[i]          = __fmul_rn(g[i], t3);
    out[NH + i]     = m[i];
    out[2 * NH + i] = be[i];
    out[3 * NH + i] = bias[i];
}

// ---------------------------------------------------------------------------
// prep: W1 signs as bf16 +/-1 bit patterns (0x3F80 / 0xBF80), row-major [col][k]
// ---------------------------------------------------------------------------
__global__ void k_pack_w1bf(const float* __restrict__ W1, unsigned short* __restrict__ wbf) {
    int k = blockIdx.x * 256 + threadIdx.x;
    int col = blockIdx.y;
    if (k >= ND) return;
    float v = W1[(size_t)col * ND + k];
    wbf[(size_t)col * ND + k] = (v >= 0.0f) ? (unsigned short)0x3F80 : (unsigned short)0xBF80;
}

// ---------------------------------------------------------------------------
// prep: W2/W3 sign bits, transposed words: wT[j*768 + col] bit l = (W[col][j*64+l] >= 0)
// ---------------------------------------------------------------------------
__global__ void k_pack_wT(const float* __restrict__ W, unsigned long long* __restrict__ wT) {
    int idx = blockIdx.x * 256 + threadIdx.x;
    if (idx >= NH * NW) return;
    int col = idx / NW, j = idx % NW;
    unsigned long long w = 0ull;
    for (int l = 0; l < 64; ++l) {
        float v = W[(size_t)col * NH + j * 64 + l];
        w |= (unsigned long long)(v >= 0.0f ? 1 : 0) << l;
    }
    wT[(size_t)j * NH + col] = w;
}

// ---------------------------------------------------------------------------
// GEMM1 replicating numpy einsum sum_of_products_contig_two (AVX512 npyv).
// Chain structure IDENTICAL to the 706us R9 kernel (bit-exact s1 output):
//   per (row,col): a[g][i] accumulates k = t*64 + g*16 + (jh*8+i), t ascending
//   (t=0..11), tail k=768.. into group 0; combine (a0+a1)+(a2+a3); level-1
//   pair-sum via shfl_xor(32) (IEEE add commutative -> bit-identical both
//   partners); tree 8/4/2/1; BN f32 op-by-op; ballot -> packed sign bits.
// R11 vs R9 (math identical, 2x register blocking):
//   - thread = (colsub, jh) computes TWO rows (2*32=64 accs). w-frag loaded +
//     unpacked ONCE, reused for both rows -> VALU instrs/MAC ~halved
//     (R9: ~64 FMA-equiv + 32 unpack per 2048 MACs; R11: 64 FMA + 32 unpack
//      per 4096 MACs). x-reads are 32-lane broadcasts (measured free in R9).
//   - block = 256 thr = 4 waves; wave w owns rows {2w,2w+1} of the block's 8;
//     32 cols per block; W staged in two k-halves (t=0..5 | t=6..11+tail),
//     ascending -> chain order unchanged.
//   - __launch_bounds__(256,3): VGPR cap ~170 under EITHER waves/EU or
//     blocks/CU interpretation -> 64 accs can NOT spill (R10 post-mortem:
//     (512,4) capped VGPR at 64 and sent a[64] to scratch -> 80 GB HBM).
//   - LDS 51,328 B -> 3 blocks/CU = 12 waves/CU.
// grid (NB/8, NH/32).
// ---------------------------------------------------------------------------
#define UNPACK_W(wA)                                                   \
    {                                                                  \
        unsigned int dw[4] = {wA.x, wA.y, wA.z, wA.w};                 \
        _Pragma("unroll")                                              \
        for (int p = 0; p < 4; ++p) {                                  \
            wf[2 * p]     = __uint_as_float(dw[p] << 16);              \
            wf[2 * p + 1] = __uint_as_float(dw[p] & 0xFFFF0000u);      \
        }                                                              \
    }

#define FMA8G(acc, G, x0, x1)                                          \
    {                                                                  \
        float xv[8] = {x0.x, x0.y, x0.z, x0.w, x1.x, x1.y, x1.z, x1.w};\
        _Pragma("unroll")                                              \
        for (int i = 0; i < 8; ++i)                                    \
            acc[G][i] = __fmaf_rn(wf[i], xv[i], acc[G][i]);            \
    }

__global__ __launch_bounds__(256, 3)
void k_gemm1_bf2(const float* __restrict__ x, const unsigned short* __restrict__ wbf,
                 const float* __restrict__ bnp, unsigned int* __restrict__ s1p32) {
    __shared__ alignas(16) float xs[8][XP];              // 25,216 B
    __shared__ alignas(16) unsigned short wl[32][WPB];   // 26,112 B

    const int tid = threadIdx.x;
    const int wave = tid >> 6, lane = tid & 63;
    const int colsub = lane & 31, jh = lane >> 5;
    const int j0 = jh * 8;
    const int r0 = blockIdx.x * 8;
    const int cb = blockIdx.y * 32;
    const int rA = 2 * wave;                 // this wave's two block-rows: rA, rA+1

    // stage x: wave stages its OWN two rows (wave-coherent, no sync needed)
    {
        const float4* s0 = (const float4*)(x + (size_t)(r0 + rA) * ND);
        const float4* s1 = (const float4*)(x + (size_t)(r0 + rA + 1) * ND);
        float4* d0 = (float4*)&xs[rA][0];
        float4* d1 = (float4*)&xs[rA + 1][0];
        for (int k4 = lane; k4 < ND / 4; k4 += 64) d0[k4] = s0[k4];
        for (int k4 = lane; k4 < ND / 4; k4 += 64) d1[k4] = s1[k4];
    }

    float a0[4][8], a1[4][8];
#pragma unroll
    for (int g = 0; g < 4; ++g)
#pragma unroll
        for (int i = 0; i < 8; ++i) { a0[g][i] = 0.0f; a1[g][i] = 0.0f; }

    const float* xr0 = &xs[rA][j0];
    const float* xr1 = &xs[rA + 1][j0];
    const unsigned short* wrow = &wl[colsub][j0];

#pragma unroll 1
    for (int half = 0; half < 2; ++half) {
        __syncthreads();   // half0: x-stage ordering for OTHER waves' w use is
                           // irrelevant (w only); half1: all waves done reading wl half0
        // stage w half: 32 cols x (48|50) uint4; 8 threads per col
        {
            const int nq = (half == 0) ? 48 : 50;    // half1 includes tail (400 bf16)
            const int c = tid >> 3, q0 = tid & 7;
            uint4* dst = (uint4*)&wl[c][0];
            const uint4* src = (const uint4*)(wbf + (size_t)(cb + c) * ND) + half * 48;
            for (int q = q0; q < nq; q += 8) dst[q] = src[q];
        }
        __syncthreads();

        const int kb = half * 384;      // global k base of this half
#pragma unroll
        for (int t = 0; t < 6; ++t) {   // global t = half*6 + t, ascending
#pragma unroll
            for (int g = 0; g < 4; ++g) {
                const int kk = t * 64 + g * 16;       // k offset within half
                uint4 wA = *(const uint4*)(wrow + kk);
                float wf[8];
                UNPACK_W(wA);
                float4 x0 = *(const float4*)(xr0 + kb + kk);
                float4 x1 = *(const float4*)(xr0 + kb + kk + 4);
                FMA8G(a0, g, x0, x1);
                float4 y0 = *(const float4*)(xr1 + kb + kk);
                float4 y1 = *(const float4*)(xr1 + kb + kk + 4);
                FMA8G(a1, g, y0, y1);
            }
        }
        if (half == 1) {
            // tail k = 768..783 (local 384..399) into group 0, after t=11
            uint4 wA = *(const uint4*)(wrow + 384);
            float wf[8];
            UNPACK_W(wA);
            float4 x0 = *(const float4*)(xr0 + 768);
            float4 x1 = *(const float4*)(xr0 + 768 + 4);
            FMA8G(a0, 0, x0, x1);
            float4 y0 = *(const float4*)(xr1 + 768);
            float4 y1 = *(const float4*)(xr1 + 768 + 4);
            FMA8G(a1, 0, y0, y1);
        }
    }

    // -------- combine + epilogue, per row: EXACT R9 sequence --------
    const int col = cb + colsub;
    const float sc = bnp[col], mm = bnp[NH + col], be = bnp[2 * NH + col],
                bias = bnp[3 * NH + col];

#pragma unroll
    for (int r = 0; r < 2; ++r) {
        float (*a)[8] = (r == 0) ? a0 : a1;   // r is unrolled -> static selection
        float v[8];
#pragma unroll
        for (int i = 0; i < 8; ++i)
            v[i] = __fadd_rn(__fadd_rn(a[0][i], a[1][i]), __fadd_rn(a[2][i], a[3][i]));
        float h8[8];
#pragma unroll
        for (int i = 0; i < 8; ++i) {
            float other = __shfl_xor(v[i], 32, 64);
            h8[i] = __fadd_rn(v[i], other);
        }
        float h4[4], h2[2];
#pragma unroll
        for (int i = 0; i < 4; ++i) h4[i] = __fadd_rn(h8[i], h8[i + 4]);
#pragma unroll
        for (int i = 0; i < 2; ++i) h2[i] = __fadd_rn(h4[i], h4[i + 2]);
        float acc = __fadd_rn(h2[0], h2[1]);

        float h  = __fadd_rn(acc, bias);
        float t1 = __fsub_rn(h, mm);
        float u  = __fmul_rn(t1, sc);
        float hb = __fadd_rn(u, be);
        unsigned long long word = __ballot(hb >= 0.0f);   // bits 0..31 = cols (jh=0)
        if (lane == 0)
            s1p32[(size_t)(r0 + rA + r) * (2 * NW) + blockIdx.y] = (unsigned int)word;
    }
}

// ---------------------------------------------------------------------------
// Binary layers 2/3: dot = 768 - 2*popcount(a XOR w) — exact integer, matches
// any-order f32 evaluation of +/-1 GEMM bit-for-bit (all partials exact).
// Epilogue faithful f32: h = fl(dot + b), BN op-by-op.
// MODE 0: sign -> packed bits. MODE 1: hardtanh -> f32 out.
// ---------------------------------------------------------------------------
template <int MODE>
__global__ __launch_bounds__(256, 2)
void k_popbin(const unsigned long long* __restrict__ Ap,
              const unsigned long long* __restrict__ wT,
              const float* __restrict__ bnp,
              unsigned long long* __restrict__ Sp, float* __restrict__ h_out) {
    __shared__ unsigned long long as[64][NW];
    const int tid = threadIdx.x;
    const int b0 = blockIdx.x * 64;

    {
        unsigned long long* asf = &as[0][0];
        const unsigned long long* src = Ap + (size_t)b0 * NW;
        for (int i = tid; i < 64 * NW; i += 256) asf[i] = src[i];
    }
    __syncthreads();

    const int wave = tid >> 6, lane = tid & 63;

    for (int chunk = 0; chunk < NW; ++chunk) {
        const int col = chunk * 64 + lane;
        unsigned long long w[NW];
#pragma unroll
        for (int j = 0; j < NW; ++j) w[j] = wT[(size_t)j * NH + col];
        const float sc = bnp[col], mm = bnp[NH + col], be = bnp[2 * NH + col],
                    bias = bnp[3 * NH + col];
        for (int r = 0; r < 16; ++r) {
            const int row = wave * 16 + r;
            int d = 0;
#pragma unroll
            for (int j = 0; j < NW; ++j)
                d += __builtin_popcountll(as[row][j] ^ w[j]);
            int dot = NH - 2 * d;
            float h  = __fadd_rn((float)dot, bias);
            float t  = __fsub_rn(h, mm);
            float u  = __fmul_rn(t, sc);
            float hb = __fadd_rn(u, be);
            if (MODE == 0) {
                unsigned long long word = __ballot(hb >= 0.0f);
                if (lane == 0) Sp[(size_t)(b0 + row) * NW + chunk] = word;
            } else {
                float hc = fminf(fmaxf(hb, -1.0f), 1.0f);
                h_out[(size_t)(b0 + row) * NH + col] = hc;
            }
        }
    }
}

// ---------------------------------------------------------------------------
// fc4 + log_softmax: one wave per row, double accumulation + shuffle reduce
// ---------------------------------------------------------------------------
__global__ __launch_bounds__(256, 4)
void k_fc4(const float* __restrict__ h3, const float* __restrict__ W4,
           const float* __restrict__ b4, float* __restrict__ out) {
    __shared__ float w4s[NC * NH];
    const int tid = threadIdx.x;
    for (int i = tid; i < NC * NH; i += 256) w4s[i] = W4[i];
    __syncthreads();

    const int wave = tid >> 6, lane = tid & 63;
    const int row = blockIdx.x * 4 + wave;
    const float* hrow = h3 + (size_t)row * NH;

    double p[NC];
#pragma unroll
    for (int c = 0; c < NC; ++c) p[c] = 0.0;

    for (int it = 0; it < NH / 64; ++it) {
        int j = it * 64 + lane;
        double hv = (double)hrow[j];
#pragma unroll
        for (int c = 0; c < NC; ++c) p[c] += hv * (double)w4s[c * NH + j];
    }
#pragma unroll
    for (int c = 0; c < NC; ++c) {
#pragma unroll
        for (int off = 32; off > 0; off >>= 1) p[c] += __shfl_xor(p[c], off, 64);
    }
    double lg[NC];
    double mx = -1e300;
#pragma unroll
    for (int c = 0; c < NC; ++c) {
        lg[c] = p[c] + (double)b4[c];
        mx = fmax(mx, lg[c]);
    }
    double s = 0.0;
#pragma unroll
    for (int c = 0; c < NC; ++c) s += exp(lg[c] - mx);
    double lse = mx + log(s);
    if (lane < NC) {
        double v = 0.0;
#pragma unroll
        for (int c = 0; c < NC; ++c)
            if (lane == c) v = lg[c];
        out[(size_t)row * NC + lane] = (float)(v - lse);
    }
}

// ---------------------------------------------------------------------------
// launch
// ---------------------------------------------------------------------------
extern "C" void kernel_launch(void* const* d_in, const int* in_sizes, int n_in,
                              void* d_out, int out_size, void* d_ws, size_t ws_size,
                              hipStream_t stream) {
    const float* x  = (const float*)d_in[0];
    const float* W1 = (const float*)d_in[1];
    const float* b1 = (const float*)d_in[2];
    const float* W2 = (const float*)d_in[3];
    const float* b2 = (const float*)d_in[4];
    const float* W3 = (const float*)d_in[5];
    const float* b3 = (const float*)d_in[6];
    const float* W4 = (const float*)d_in[7];
    const float* b4 = (const float*)d_in[8];
    const float* g1 = (const float*)d_in[9],  *be1 = (const float*)d_in[10];
    const float* m1 = (const float*)d_in[11], *v1  = (const float*)d_in[12];
    const float* g2 = (const float*)d_in[13], *be2 = (const float*)d_in[14];
    const float* m2 = (const float*)d_in[15], *v2  = (const float*)d_in[16];
    const float* g3 = (const float*)d_in[17], *be3 = (const float*)d_in[18];
    const float* m3 = (const float*)d_in[19], *v3  = (const float*)d_in[20];
    float* out = (float*)d_out;

    char* ws = (char*)d_ws;
    size_t off = 0;
    unsigned short* wbf = (unsigned short*)(ws + off);  off += (size_t)NH * ND * 2;
    unsigned long long* w2pT = (unsigned long long*)(ws + off); off += (size_t)NW * NH * 8;
    unsigned long long* w3pT = (unsigned long long*)(ws + off); off += (size_t)NW * NH * 8;
    unsigned long long* s1p  = (unsigned long long*)(ws + off); off += (size_t)NB * NW * 8;
    unsigned long long* s2p  = (unsigned long long*)(ws + off); off += (size_t)NB * NW * 8;
    float*  h3   = (float*)(ws + off);              off += (size_t)NB * NH * 4;
    float* bnp1 = (float*)(ws + off);               off += (size_t)4 * NH * 4;
    float* bnp2 = (float*)(ws + off);               off += (size_t)4 * NH * 4;
    float* bnp3 = (float*)(ws + off);               off += (size_t)4 * NH * 4;
    (void)ws_size; (void)in_sizes; (void)n_in; (void)out_size;

    // prep
    k_pack_w1bf<<<dim3(4, NH), 256, 0, stream>>>(W1, wbf);
    k_pack_wT<<<dim3((NH * NW + 255) / 256), 256, 0, stream>>>(W2, w2pT);
    k_pack_wT<<<dim3((NH * NW + 255) / 256), 256, 0, stream>>>(W3, w3pT);
    k_bnprep_f32<<<dim3(3), 256, 0, stream>>>(g1, be1, m1, v1, b1, bnp1);
    k_bnprep_f32<<<dim3(3), 256, 0, stream>>>(g2, be2, m2, v2, b2, bnp2);
    k_bnprep_f32<<<dim3(3), 256, 0, stream>>>(g3, be3, m3, v3, b3, bnp3);

    // layers
    k_gemm1_bf2<<<dim3(NB / 8, NH / 32), 256, 0, stream>>>(x, wbf, bnp1,
                                                           (unsigned int*)s1p);
    k_popbin<0><<<dim3(NB / 64), 256, 0, stream>>>(s1p, w2pT, bnp2, s2p, nullptr);
    k_popbin<1><<<dim3(NB / 64), 256, 0, stream>>>(s2p, w3pT, bnp3, nullptr, h3);
    k_fc4<<<dim3(NB / 4), 256, 0, stream>>>(h3, W4, b4, out);
}

// Round 3
// 1679.164 us; speedup vs baseline: 10.3308x; 7.4434x over previous
//
#include <hip/hip_runtime.h>
#include <math.h>
#include <stdint.h>

// Problem dims
#define NB 16384    // batch
#define NH 768      // hidden
#define ND 784      // input features
#define NC 10       // classes
#define NW 12       // u64 words per 768-bit row

// gemm1 tiling
#define XP 788      // xs row pitch (f32): 197 quads, odd -> spread bank groups
#define WPF 404     // wl col pitch (f32): 101 quads, odd; holds up to 400 elems (one half)

// ---------------------------------------------------------------------------
// prep: BN params in FAITHFUL f32 (replicating np op-by-op):
// sc = g * (1 / sqrt(v + 1e-5)), each op f32-rounded. [0]=sc,[1]=m,[2]=be,[3]=bias
// ---------------------------------------------------------------------------
__global__ void k_bnprep_f32(const float* __restrict__ g, const float* __restrict__ be,
                             const float* __restrict__ m, const float* __restrict__ v,
                             const float* __restrict__ bias, float* __restrict__ out) {
    int i = blockIdx.x * 256 + threadIdx.x;
    if (i >= NH) return;
    float t1 = __fadd_rn(v[i], 1e-5f);
    float t2 = __fsqrt_rn(t1);
    float t3 = __fdiv_rn(1.0f, t2);
    out[i]          = __fmul_rn(g[i], t3);
    out[NH + i]     = m[i];
    out[2 * NH + i] = be[i];
    out[3 * NH + i] = bias[i];
}

// ---------------------------------------------------------------------------
// prep: W1 signs as f32 +/-1 (no per-use unpack in the GEMM hot loop)
// ---------------------------------------------------------------------------
__global__ void k_pack_w1f32(const float* __restrict__ W1, float* __restrict__ wf) {
    int i = blockIdx.x * 256 + threadIdx.x;
    if (i < NH * ND) wf[i] = (W1[i] >= 0.0f) ? 1.0f : -1.0f;
}

// ---------------------------------------------------------------------------
// prep: W2/W3 sign bits, transposed words: wT[j*768 + col] bit l = (W[col][j*64+l] >= 0)
// ---------------------------------------------------------------------------
__global__ void k_pack_wT(const float* __restrict__ W, unsigned long long* __restrict__ wT) {
    int idx = blockIdx.x * 256 + threadIdx.x;
    if (idx >= NH * NW) return;
    int col = idx / NW, j = idx % NW;
    unsigned long long w = 0ull;
    for (int l = 0; l < 64; ++l) {
        float v = W[(size_t)col * NH + j * 64 + l];
        w |= (unsigned long long)(v >= 0.0f ? 1 : 0) << l;
    }
    wT[(size_t)j * NH + col] = w;
}

// ---------------------------------------------------------------------------
// GEMM1 replicating numpy einsum sum_of_products_contig_two (AVX512 npyv).
// Chain structure IDENTICAL to the 706us R9 kernel (bit-exact s1 output):
//   per (row,col): chain(g,j) accumulates k = t*64 + g*16 + j (j = jh*8+i),
//   t = 0..11 ascending, tail k=768.. into g=0; combine
//   v[j] = (a0+a1)+(a2+a3); h8 = v_jh0 + v_jh1 (xor32); tree 8/4/2/1;
//   BN f32 op-by-op; sign bits packed.
// R12 vs R9 (math identical, lane-remap + f32 weights):
//   - thread = (colsub in [0,16), gh, jh): owns g in {2gh, 2gh+1} (16 chains)
//     for TWO rows -> 32 accumulators total (R9's proven no-spill budget),
//     shaped a0[2][8], a1[2][8] with tiny-unrolled static indices only.
//     NO pointer selects / address-escapes (R11 post-mortem: SROA failure
//     sent the accs to scratch; 27.8 GB scratch writes).
//   - g-pair combine via one extra shfl_xor(16); IEEE add commutative ->
//     bit-identical v[] on all lanes; rest of tree exactly R9.
//   - W staged as f32 +/-1: unpack VALU ops eliminated (~0.5x VALU/MAC);
//     w LDS bytes amortized over 2 rows.
//   - __launch_bounds__(512, 2): measured semantics = min BLOCKS/CU
//     (R9/R10 (512,4) -> 8 waves/EU -> 64-VGPR cap, both measured 64).
//     2 blocks/CU -> 4 waves/EU -> 128-VGPR cap >> ~80 live.
// Block: 512 thr = 8 waves, wave (wr=wave>>1, wc=wave&1): rows {2wr,2wr+1},
// cols cb + wc*16 + colsub. Block = 8 rows x 32 cols; LDS 76,996 B -> 2 blk/CU.
// grid (NB/8, NH/32).
// ---------------------------------------------------------------------------
#define FMA8F(A, GL, W0, W1, X0, X1)                         \
    A[GL][0] = __fmaf_rn((W0).x, (X0).x, A[GL][0]);          \
    A[GL][1] = __fmaf_rn((W0).y, (X0).y, A[GL][1]);          \
    A[GL][2] = __fmaf_rn((W0).z, (X0).z, A[GL][2]);          \
    A[GL][3] = __fmaf_rn((W0).w, (X0).w, A[GL][3]);          \
    A[GL][4] = __fmaf_rn((W1).x, (X1).x, A[GL][4]);          \
    A[GL][5] = __fmaf_rn((W1).y, (X1).y, A[GL][5]);          \
    A[GL][6] = __fmaf_rn((W1).z, (X1).z, A[GL][6]);          \
    A[GL][7] = __fmaf_rn((W1).w, (X1).w, A[GL][7]);

// combine + epilogue for one row; A = acc array name (direct, no pointer)
#define COMB_EPI(A, ROWOFF)                                                  \
    {                                                                        \
        float p[8];                                                          \
        _Pragma("unroll")                                                    \
        for (int i = 0; i < 8; ++i) p[i] = __fadd_rn(A[0][i], A[1][i]);      \
        float v[8];                                                          \
        _Pragma("unroll")                                                    \
        for (int i = 0; i < 8; ++i) {                                        \
            float o = __shfl_xor(p[i], 16, 64);                              \
            v[i] = __fadd_rn(p[i], o);                                       \
        }                                                                    \
        float h8[8];                                                         \
        _Pragma("unroll")                                                    \
        for (int i = 0; i < 8; ++i) {                                        \
            float o = __shfl_xor(v[i], 32, 64);                              \
            h8[i] = __fadd_rn(v[i], o);                                      \
        }                                                                    \
        float h4[4], h2[2];                                                  \
        _Pragma("unroll")                                                    \
        for (int i = 0; i < 4; ++i) h4[i] = __fadd_rn(h8[i], h8[i + 4]);     \
        _Pragma("unroll")                                                    \
        for (int i = 0; i < 2; ++i) h2[i] = __fadd_rn(h4[i], h4[i + 2]);     \
        float acc = __fadd_rn(h2[0], h2[1]);                                 \
        float h  = __fadd_rn(acc, bias);                                     \
        float t1 = __fsub_rn(h, mm);                                         \
        float u  = __fmul_rn(t1, sc);                                        \
        float hb = __fadd_rn(u, be);                                         \
        unsigned long long word = __ballot(hb >= 0.0f);                      \
        if (lane == 0)                                                       \
            atomicOr(&sbits[rA + (ROWOFF)],                                  \
                     ((unsigned int)(word & 0xFFFFull)) << (16 * wc));       \
    }

__global__ __launch_bounds__(512, 2)
void k_gemm1_g2(const float* __restrict__ x, const float* __restrict__ wf,
                const float* __restrict__ bnp, unsigned int* __restrict__ s1p32) {
    __shared__ alignas(16) float xs[8][XP];    // 25,216 B
    __shared__ alignas(16) float wl[32][WPF];  // 51,712 B
    __shared__ unsigned int sbits[8];          // one u32 per block-row

    const int tid = threadIdx.x;
    const int wave = tid >> 6, lane = tid & 63;
    const int colsub = lane & 15;
    const int gh = (lane >> 4) & 1;
    const int jh = lane >> 5;
    const int wr = wave >> 1, wc = wave & 1;
    const int rA = 2 * wr;
    const int r0 = blockIdx.x * 8;
    const int cb = blockIdx.y * 32;

    if (tid < 8) sbits[tid] = 0;

    // stage x: wave w stages block-row w (196 float4, lane-strided, coalesced)
    {
        const float4* src = (const float4*)(x + (size_t)(r0 + wave) * ND);
        float4* dst = (float4*)&xs[wave][0];
        for (int k4 = lane; k4 < ND / 4; k4 += 64) dst[k4] = src[k4];
    }

    float a0[2][8], a1[2][8];
#pragma unroll
    for (int gl = 0; gl < 2; ++gl)
#pragma unroll
        for (int i = 0; i < 8; ++i) { a0[gl][i] = 0.0f; a1[gl][i] = 0.0f; }

    const float* xr0 = &xs[rA][0];
    const float* xr1 = &xs[rA + 1][0];
    const float* wcol = &wl[wc * 16 + colsub][0];

#pragma unroll 1
    for (int half = 0; half < 2; ++half) {
        __syncthreads();  // half0: orders x-stage; half1: all waves done with wl half0
        // stage w half: 32 cols x (96|100) float4 of f32 +/-1; 16 threads/col
        {
            const int c = tid >> 4, q0 = tid & 15;
            const int nq = (half == 0) ? 96 : 100;
            const float4* src = (const float4*)(wf + (size_t)(cb + c) * ND) + half * 96;
            float4* dst = (float4*)&wl[c][0];
            for (int q = q0; q < nq; q += 16) dst[q] = src[q];
        }
        __syncthreads();

#pragma unroll
        for (int t = 0; t < 6; ++t) {                // global t = half*6 + t, ascending
            const int lb = t * 64;                   // local (in-half) k base
            const int kb = half * 384 + lb;          // global k base
#pragma unroll
            for (int gl = 0; gl < 2; ++gl) {
                const int off = 32 * gh + 16 * gl + 8 * jh;
                float4 wA = *(const float4*)(wcol + lb + off);
                float4 wB = *(const float4*)(wcol + lb + off + 4);
                float4 x0 = *(const float4*)(xr0 + kb + off);
                float4 x1 = *(const float4*)(xr0 + kb + off + 4);
                FMA8F(a0, gl, wA, wB, x0, x1);
                float4 y0 = *(const float4*)(xr1 + kb + off);
                float4 y1 = *(const float4*)(xr1 + kb + off + 4);
                FMA8F(a1, gl, wA, wB, y0, y1);
            }
        }
        if (half == 1) {
            // tail k = 768..783 into g = 0 (gh=0, gl=0 threads), after t=11
            if (gh == 0) {
                const int lk = 384 + 8 * jh;         // local wl index
                const int gk = 768 + 8 * jh;         // global x index
                float4 wA = *(const float4*)(wcol + lk);
                float4 wB = *(const float4*)(wcol + lk + 4);
                float4 x0 = *(const float4*)(xr0 + gk);
                float4 x1 = *(const float4*)(xr0 + gk + 4);
                FMA8F(a0, 0, wA, wB, x0, x1);
                float4 y0 = *(const float4*)(xr1 + gk);
                float4 y1 = *(const float4*)(xr1 + gk + 4);
                FMA8F(a1, 0, wA, wB, y0, y1);
            }
        }
    }

    // -------- combine + epilogue (exact R9 op sequence per row) --------
    const int col = cb + wc * 16 + colsub;
    const float sc = bnp[col], mm = bnp[NH + col], be = bnp[2 * NH + col],
                bias = bnp[3 * NH + col];

    COMB_EPI(a0, 0)
    COMB_EPI(a1, 1)

    __syncthreads();
    if (tid < 8)
        s1p32[(size_t)(r0 + tid) * (2 * NW) + blockIdx.y] = sbits[tid];
}

// ---------------------------------------------------------------------------
// Binary layers 2/3: dot = 768 - 2*popcount(a XOR w) — exact integer, matches
// any-order f32 evaluation of +/-1 GEMM bit-for-bit (all partials exact).
// Epilogue faithful f32: h = fl(dot + b), BN op-by-op.
// MODE 0: sign -> packed bits. MODE 1: hardtanh -> f32 out.
// ---------------------------------------------------------------------------
template <int MODE>
__global__ __launch_bounds__(256, 2)
void k_popbin(const unsigned long long* __restrict__ Ap,
              const unsigned long long* __restrict__ wT,
              const float* __restrict__ bnp,
              unsigned long long* __restrict__ Sp, float* __restrict__ h_out) {
    __shared__ unsigned long long as[64][NW];
    const int tid = threadIdx.x;
    const int b0 = blockIdx.x * 64;

    {
        unsigned long long* asf = &as[0][0];
        const unsigned long long* src = Ap + (size_t)b0 * NW;
        for (int i = tid; i < 64 * NW; i += 256) asf[i] = src[i];
    }
    __syncthreads();

    const int wave = tid >> 6, lane = tid & 63;

    for (int chunk = 0; chunk < NW; ++chunk) {
        const int col = chunk * 64 + lane;
        unsigned long long w[NW];
#pragma unroll
        for (int j = 0; j < NW; ++j) w[j] = wT[(size_t)j * NH + col];
        const float sc = bnp[col], mm = bnp[NH + col], be = bnp[2 * NH + col],
                    bias = bnp[3 * NH + col];
        for (int r = 0; r < 16; ++r) {
            const int row = wave * 16 + r;
            int d = 0;
#pragma unroll
            for (int j = 0; j < NW; ++j)
                d += __builtin_popcountll(as[row][j] ^ w[j]);
            int dot = NH - 2 * d;
            float h  = __fadd_rn((float)dot, bias);
            float t  = __fsub_rn(h, mm);
            float u  = __fmul_rn(t, sc);
            float hb = __fadd_rn(u, be);
            if (MODE == 0) {
                unsigned long long word = __ballot(hb >= 0.0f);
                if (lane == 0) Sp[(size_t)(b0 + row) * NW + chunk] = word;
            } else {
                float hc = fminf(fmaxf(hb, -1.0f), 1.0f);
                h_out[(size_t)(b0 + row) * NH + col] = hc;
            }
        }
    }
}

// ---------------------------------------------------------------------------
// fc4 + log_softmax: one wave per row, double accumulation + shuffle reduce
// ---------------------------------------------------------------------------
__global__ __launch_bounds__(256, 4)
void k_fc4(const float* __restrict__ h3, const float* __restrict__ W4,
           const float* __restrict__ b4, float* __restrict__ out) {
    __shared__ float w4s[NC * NH];
    const int tid = threadIdx.x;
    for (int i = tid; i < NC * NH; i += 256) w4s[i] = W4[i];
    __syncthreads();

    const int wave = tid >> 6, lane = tid & 63;
    const int row = blockIdx.x * 4 + wave;
    const float* hrow = h3 + (size_t)row * NH;

    double p[NC];
#pragma unroll
    for (int c = 0; c < NC; ++c) p[c] = 0.0;

    for (int it = 0; it < NH / 64; ++it) {
        int j = it * 64 + lane;
        double hv = (double)hrow[j];
#pragma unroll
        for (int c = 0; c < NC; ++c) p[c] += hv * (double)w4s[c * NH + j];
    }
#pragma unroll
    for (int c = 0; c < NC; ++c) {
#pragma unroll
        for (int off = 32; off > 0; off >>= 1) p[c] += __shfl_xor(p[c], off, 64);
    }
    double lg[NC];
    double mx = -1e300;
#pragma unroll
    for (int c = 0; c < NC; ++c) {
        lg[c] = p[c] + (double)b4[c];
        mx = fmax(mx, lg[c]);
    }
    double s = 0.0;
#pragma unroll
    for (int c = 0; c < NC; ++c) s += exp(lg[c] - mx);
    double lse = mx + log(s);
    if (lane < NC) {
        double v = 0.0;
#pragma unroll
        for (int c = 0; c < NC; ++c)
            if (lane == c) v = lg[c];
        out[(size_t)row * NC + lane] = (float)(v - lse);
    }
}

// ---------------------------------------------------------------------------
// launch
// ---------------------------------------------------------------------------
extern "C" void kernel_launch(void* const* d_in, const int* in_sizes, int n_in,
                              void* d_out, int out_size, void* d_ws, size_t ws_size,
                              hipStream_t stream) {
    const float* x  = (const float*)d_in[0];
    const float* W1 = (const float*)d_in[1];
    const float* b1 = (const float*)d_in[2];
    const float* W2 = (const float*)d_in[3];
    const float* b2 = (const float*)d_in[4];
    const float* W3 = (const float*)d_in[5];
    const float* b3 = (const float*)d_in[6];
    const float* W4 = (const float*)d_in[7];
    const float* b4 = (const float*)d_in[8];
    const float* g1 = (const float*)d_in[9],  *be1 = (const float*)d_in[10];
    const float* m1 = (const float*)d_in[11], *v1  = (const float*)d_in[12];
    const float* g2 = (const float*)d_in[13], *be2 = (const float*)d_in[14];
    const float* m2 = (const float*)d_in[15], *v2  = (const float*)d_in[16];
    const float* g3 = (const float*)d_in[17], *be3 = (const float*)d_in[18];
    const float* m3 = (const float*)d_in[19], *v3  = (const float*)d_in[20];
    float* out = (float*)d_out;

    char* ws = (char*)d_ws;
    size_t off = 0;
    float* wf32 = (float*)(ws + off);               off += (size_t)NH * ND * 4;  // 2,408,448
    unsigned long long* w2pT = (unsigned long long*)(ws + off); off += (size_t)NW * NH * 8;
    unsigned long long* w3pT = (unsigned long long*)(ws + off); off += (size_t)NW * NH * 8;
    unsigned long long* s1p  = (unsigned long long*)(ws + off); off += (size_t)NB * NW * 8;
    unsigned long long* s2p  = (unsigned long long*)(ws + off); off += (size_t)NB * NW * 8;
    float*  h3   = (float*)(ws + off);              off += (size_t)NB * NH * 4;
    float* bnp1 = (float*)(ws + off);               off += (size_t)4 * NH * 4;
    float* bnp2 = (float*)(ws + off);               off += (size_t)4 * NH * 4;
    float* bnp3 = (float*)(ws + off);               off += (size_t)4 * NH * 4;
    (void)ws_size; (void)in_sizes; (void)n_in; (void)out_size;

    // prep
    k_pack_w1f32<<<dim3((NH * ND + 255) / 256), 256, 0, stream>>>(W1, wf32);
    k_pack_wT<<<dim3((NH * NW + 255) / 256), 256, 0, stream>>>(W2, w2pT);
    k_pack_wT<<<dim3((NH * NW + 255) / 256), 256, 0, stream>>>(W3, w3pT);
    k_bnprep_f32<<<dim3(3), 256, 0, stream>>>(g1, be1, m1, v1, b1, bnp1);
    k_bnprep_f32<<<dim3(3), 256, 0, stream>>>(g2, be2, m2, v2, b2, bnp2);
    k_bnprep_f32<<<dim3(3), 256, 0, stream>>>(g3, be3, m3, v3, b3, bnp3);

    // layers
    k_gemm1_g2<<<dim3(NB / 8, NH / 32), 512, 0, stream>>>(x, wf32, bnp1,
                                                          (unsigned int*)s1p);
    k_popbin<0><<<dim3(NB / 64), 256, 0, stream>>>(s1p, w2pT, bnp2, s2p, nullptr);
    k_popbin<1><<<dim3(NB / 64), 256, 0, stream>>>(s2p, w3pT, bnp3, nullptr, h3);
    k_fc4<<<dim3(NB / 4), 256, 0, stream>>>(h3, W4, b4, out);
}